// Round 20
// baseline (66.915 us; speedup 1.0000x reference)
//
#include <hip/hip_runtime.h>
#include <hip/hip_bf16.h>
#include <stdint.h>

#define NROWS 8192
#define DIM 512

typedef short bf16x8 __attribute__((ext_vector_type(8)));
typedef float f32x4 __attribute__((ext_vector_type(4)));

__device__ __forceinline__ unsigned short f2bf(float f) {
    union { float f; uint32_t u; } c; c.f = f;
    uint32_t u = c.u;
    return (unsigned short)((u + 0x7FFFu + ((u >> 16) & 1u)) >> 16);
}

__device__ __forceinline__ void gload16(const unsigned short* g, unsigned short* l) {
    __builtin_amdgcn_global_load_lds((const __attribute__((address_space(1))) void*)g,
                                     (__attribute__((address_space(3))) void*)l,
                                     16, 0, 0);
}

// ---------------- Kernel 1: L2-normalize rows -> bf16; zero out[0] + split-lin slots --
__global__ __launch_bounds__(256) void knorm(const float* __restrict__ in,
                                             unsigned short* __restrict__ out,
                                             float* __restrict__ part,
                                             float* __restrict__ loss_out) {
    if (blockIdx.x == 0 && threadIdx.x == 0) loss_out[0] = 0.0f;
    if (blockIdx.x < 16) {   // zero the 16 split-tile partial slots (sixteenths atomicAdd)
        part[((164 + blockIdx.x) << 9) + threadIdx.x] = 0.0f;
        part[((164 + blockIdx.x) << 9) + 256 + threadIdx.x] = 0.0f;
    }
    const int row  = (blockIdx.x << 2) + (threadIdx.x >> 6);
    const int lane = threadIdx.x & 63;
    const float4* src = (const float4*)(in + (size_t)row * DIM);
    float4 a = src[lane];
    float4 b = src[lane + 64];
    float ss = a.x*a.x + a.y*a.y + a.z*a.z + a.w*a.w
             + b.x*b.x + b.y*b.y + b.z*b.z + b.w*b.w;
    #pragma unroll
    for (int m = 1; m < 64; m <<= 1) ss += __shfl_xor(ss, m);
    const float inv = 1.0f / sqrtf(ss);
    ushort4* dst = (ushort4*)(out + (size_t)row * DIM);
    ushort4 o;
    o.x = f2bf(a.x*inv); o.y = f2bf(a.y*inv); o.z = f2bf(a.z*inv); o.w = f2bf(a.w*inv);
    dst[lane] = o;
    o.x = f2bf(b.x*inv); o.y = f2bf(b.y*inv); o.z = f2bf(b.z*inv); o.w = f2bf(b.w*inv);
    dst[lane + 64] = o;
}

// ---------------- Kernel 2: 512 full 256^2 tiles + 256 sixteenth (64^2) tiles --------
// Full path = R13/R14/R18 verbatim (session best). The 16 split tiles (lins
// 164..179, supertile (0,3), all off-diagonal) are now covered by 256
// SIXTEENTH blocks (64x64 each): half the staging (1 gload16/thread/step,
// vmcnt(1)) and 1/16 the MFMA of a full tile at FULL issue width -> tail
// round ~4-5us vs quarter's 8.6. Same proven swizzle invariants: A staged
// by waves 0-7, B by waves 8-15 (row&7 == l>>3 both), ds_read XOR gk^(l&7)
// valid since rr&7 == l&7. Results atomicAdd into pre-zeroed split slots.
__global__ __launch_bounds__(1024, 1) void kgemm(const unsigned short* __restrict__ E,
                                                 float* __restrict__ part,
                                                 float* __restrict__ pospart) {
    __shared__ unsigned short lds[2][2][256 * 64];   // full: 256 rows; sixteenth uses 64

    const int tid = threadIdx.x;
    const int w = tid >> 6;          // 0..15
    const int l = tid & 63;
    const int xcd  = blockIdx.x & 7;
    const int slot = blockIdx.x >> 3;                // 0..95
    const int g_src = (l & 7) ^ (l >> 3);   // inverse-swizzled source 16B-group

    if (slot >= 64) {
        // ===== SIXTEENTH: 64x64 pure-negative, all 16 waves (4x4 of 16x16) =====
        const int q   = (xcd << 5) + (slot - 64);    // 0..255
        const int p   = q >> 4;                      // parent 0..15
        const int lin = 164 + p;
        const int bi = p >> 3, bj = 24 + (p & 7);
        const int qroff = ((q >> 2) & 3) << 6;       // sub-row offset in parent
        const int qcoff = (q & 3) << 6;              // sub-col offset in parent
        const int brow = (bi << 8) + qroff;
        const int bcol = (bj << 8) + qcoff;
        const int wr = (w >> 2) << 4;                // 0,16,32,48
        const int wc = (w & 3) << 4;                 // 0,16,32,48

        f32x4 acc = (f32x4)0.0f;

        auto STAGE16 = [&](int buf, int kt) {
            const size_t colb = (size_t)((kt << 6) + (g_src << 3));
            if (tid < 512) {                         // waves 0-7 stage A
                const int r = (w << 3) + (l >> 3);   // 0..63, r&7 == l>>3
                gload16(E + (size_t)(brow + r) * DIM + colb, &lds[buf][0][w << 9]);
            } else {                                 // waves 8-15 stage B
                const int r = ((w - 8) << 3) + (l >> 3);
                gload16(E + (size_t)(bcol + r) * DIM + colb, &lds[buf][1][(w - 8) << 9]);
            }
        };
        auto COMPUTE16 = [&](int buf) {
            const unsigned short* sA = lds[buf][0];
            const unsigned short* sB = lds[buf][1];
            #pragma unroll
            for (int kk = 0; kk < 2; kk++) {
                const int gk  = (kk << 2) + (l >> 4);
                const int gsw = (gk ^ (l & 7)) << 3;
                bf16x8 aF = *(const bf16x8*)&sA[((wr + (l & 15)) << 6) + gsw];
                bf16x8 bF = *(const bf16x8*)&sB[((wc + (l & 15)) << 6) + gsw];
                acc = __builtin_amdgcn_mfma_f32_16x16x32_bf16(aF, bF, acc, 0, 0, 0);
            }
        };

        STAGE16(0, 0);
        #pragma unroll
        for (int kt = 0; kt < 8; kt++) {
            if (kt > 0) __builtin_amdgcn_s_barrier();
            if (kt < 7) {
                STAGE16((kt + 1) & 1, kt + 1);
                asm volatile("s_waitcnt vmcnt(1)" ::: "memory");
            } else {
                asm volatile("s_waitcnt vmcnt(0)" ::: "memory");
            }
            __builtin_amdgcn_sched_barrier(0);
            __builtin_amdgcn_s_barrier();
            COMPUTE16(kt & 1);
        }

        float c = 0.0f;
        #pragma unroll
        for (int r = 0; r < 4; r++) {
            const int lrow = wr + ((l >> 4) << 2) + r;       // 0..63
            const float e = __expf(fmaf(acc[r], 10.0f, -10.0f));
            c += e;
            float n = e;
            #pragma unroll
            for (int m = 1; m < 16; m <<= 1) n += __shfl_xor(n, m);
            if ((l & 15) == 0)
                atomicAdd(&part[((size_t)lin << 9) + qroff + lrow], n);
        }
        c += __shfl_xor(c, 16);
        c += __shfl_xor(c, 32);
        if ((l >> 4) == 0)                                   // l = 0..15 -> col wc+l
            atomicAdd(&part[((size_t)lin << 9) + 256 + qcoff + wc + l], c);
        return;
    }

    // ================= FULL: 256x256 tile (R18 verbatim) =============================
    const int f   = (xcd << 6) + slot;               // 0..511
    const int lin = f + (f >= 164 ? 16 : 0);         // skip split set 164..179
    int rem = lin;
    int SI = -1, SJ = -1;
    #pragma unroll
    for (int s = 0; s < 10; s++) {
        constexpr int si_t[10] = {0,0,0,0,1,1,1,2,2,3};
        constexpr int sj_t[10] = {0,1,2,3,1,2,3,2,3,3};
        const int sz = (si_t[s] == sj_t[s]) ? 36 : 64;
        if (SI < 0) {
            if (rem < sz) { SI = si_t[s]; SJ = sj_t[s]; }
            else rem -= sz;
        }
    }
    int bi, bj;
    if (SI == SJ) {
        int x = 0;
        while (rem >= 8 - x) { rem -= 8 - x; x++; }
        bi = (SI << 3) + x; bj = (SI << 3) + x + rem;
    } else {
        bi = (SI << 3) + (rem >> 3);
        bj = (SJ << 3) + (rem & 7);
    }

    const int brow = bi << 8;
    const int bcol = bj << 8;
    const int wr = (w >> 2) << 6;
    const int wc = (w & 3) << 6;

    f32x4 acc[4][4];
    #pragma unroll
    for (int i = 0; i < 4; i++)
        #pragma unroll
        for (int j = 0; j < 4; j++) acc[i][j] = (f32x4)0.0f;

    auto STAGE = [&](int buf, int kt) {
        const size_t colb = (size_t)((kt << 6) + (g_src << 3));
        #pragma unroll
        for (int s = 0; s < 2; s++) {
            const int rb = (w << 4) + (s << 3);
            const int r  = rb + (l >> 3);
            gload16(E + (size_t)(brow + r) * DIM + colb, &lds[buf][0][rb << 6]);
            gload16(E + (size_t)(bcol + r) * DIM + colb, &lds[buf][1][rb << 6]);
        }
    };

    auto COMPUTE = [&](int buf) {
        const unsigned short* sA = lds[buf][0];
        const unsigned short* sB = lds[buf][1];
        #pragma unroll
        for (int kk = 0; kk < 2; kk++) {
            bf16x8 aF[4], bF[4];
            const int gk  = (kk << 2) + (l >> 4);
            const int gsw = (gk ^ (l & 7)) << 3;
            #pragma unroll
            for (int mi = 0; mi < 4; mi++) {
                const int rr = wr + (mi << 4) + (l & 15);
                aF[mi] = *(const bf16x8*)&sA[(rr << 6) + gsw];
            }
            #pragma unroll
            for (int ni = 0; ni < 4; ni++) {
                const int rr = wc + (ni << 4) + (l & 15);
                bF[ni] = *(const bf16x8*)&sB[(rr << 6) + gsw];
            }
            #pragma unroll
            for (int mi = 0; mi < 4; mi++)
                #pragma unroll
                for (int ni = 0; ni < 4; ni++)
                    acc[mi][ni] = __builtin_amdgcn_mfma_f32_16x16x32_bf16(
                        aF[mi], bF[ni], acc[mi][ni], 0, 0, 0);
        }
    };

    STAGE(0, 0);
    #pragma unroll
    for (int kt = 0; kt < 8; kt++) {
        if (kt > 0) __builtin_amdgcn_s_barrier();
        if (kt < 7) {
            STAGE((kt + 1) & 1, kt + 1);
            asm volatile("s_waitcnt vmcnt(4)" ::: "memory");
        } else {
            asm volatile("s_waitcnt vmcnt(0)" ::: "memory");
        }
        __builtin_amdgcn_sched_barrier(0);
        __builtin_amdgcn_s_barrier();
        COMPUTE(kt & 1);
    }

    float* lds_row = (float*)&lds[0][0][0];       // [4][256]
    float* lds_col = lds_row + 1024;              // [4][256]
    float* lds_pos = lds_row + 2048;              // [4][256]

    __syncthreads();

    if (bi == bj) {
        #pragma unroll
        for (int mi = 0; mi < 4; mi++) {
            #pragma unroll
            for (int r = 0; r < 4; r++) {
                const int lrow = wr + (mi << 4) + ((l >> 4) << 2) + r;
                const int gi = brow + lrow;
                float p = 0.0f, n = 0.0f;
                #pragma unroll
                for (int ni = 0; ni < 4; ni++) {
                    const int gj = bcol + wc + (ni << 4) + (l & 15);
                    const float e = __expf(fmaf(acc[mi][ni][r], 10.0f, -10.0f));
                    if (gi == gj) {
                    } else if ((gi >> 2) == (gj >> 2)) {
                        p += e;
                    } else {
                        n += e;
                    }
                }
                #pragma unroll
                for (int m = 1; m < 16; m <<= 1) {
                    n += __shfl_xor(n, m);
                    p += __shfl_xor(p, m);
                }
                if ((l & 15) == 0) {
                    lds_row[((w & 3) << 8) + lrow] = n;
                    lds_pos[((w & 3) << 8) + lrow] = p;
                }
            }
        }
    } else {
        float c[4] = {0.0f, 0.0f, 0.0f, 0.0f};
        #pragma unroll
        for (int mi = 0; mi < 4; mi++) {
            #pragma unroll
            for (int r = 0; r < 4; r++) {
                const int lrow = wr + (mi << 4) + ((l >> 4) << 2) + r;
                float n = 0.0f;
                #pragma unroll
                for (int ni = 0; ni < 4; ni++) {
                    const float e = __expf(fmaf(acc[mi][ni][r], 10.0f, -10.0f));
                    n += e;
                    c[ni] += e;
                }
                #pragma unroll
                for (int m = 1; m < 16; m <<= 1) n += __shfl_xor(n, m);
                if ((l & 15) == 0) lds_row[((w & 3) << 8) + lrow] = n;
            }
        }
        #pragma unroll
        for (int ni = 0; ni < 4; ni++) {
            c[ni] += __shfl_xor(c[ni], 16);
            c[ni] += __shfl_xor(c[ni], 32);
            if ((l >> 4) == 0)
                lds_col[((w >> 2) << 8) + wc + (ni << 4) + l] = c[ni];
        }
    }
    __syncthreads();

    if (tid < 256) {
        const float s = lds_row[tid] + lds_row[256 + tid]
                      + lds_row[512 + tid] + lds_row[768 + tid];
        part[((size_t)lin << 9) + tid] = s;
    } else if (tid < 512) {
        if (bi != bj) {
            const int cc = tid - 256;
            const float s = lds_col[cc] + lds_col[256 + cc]
                          + lds_col[512 + cc] + lds_col[768 + cc];
            part[((size_t)lin << 9) + 256 + cc] = s;
        }
    } else if (tid < 768) {
        if (bi == bj) {
            const int rr = tid - 512;
            const float s = lds_pos[rr] + lds_pos[256 + rr]
                          + lds_pos[512 + rr] + lds_pos[768 + rr];
            pospart[(bi << 8) + rr] = s;
        }
    }
}

// ---------------- Kernel 3: gather partials, compute loss, reduce ----------------
__global__ __launch_bounds__(128) void kred(const float* __restrict__ part,
                                            const float* __restrict__ pospart,
                                            float* __restrict__ out) {
    const int T = blockIdx.x >> 1;
    const int r = ((blockIdx.x & 1) << 7) + threadIdx.x;   // 0..255 within T's group

    auto linof = [](int a, int b) {   // a <= b, 0..31
        constexpr int base[4][4] = {{0, 36, 100, 164},
                                    {0, 228, 264, 328},
                                    {0, 0, 392, 428},
                                    {0, 0, 0, 492}};
        const int SI = a >> 3, SJ = b >> 3, x = a & 7, y = b & 7;
        int inner;
        if (SI == SJ) inner = (x << 3) - ((x * (x - 1)) >> 1) + (y - x);
        else          inner = (x << 3) + y;
        return base[SI][SJ] + inner;
    };

    float n = 0.0f;
    for (int bj = T; bj < 32; bj++)
        n += part[((size_t)linof(T, bj) << 9) + r];
    for (int bi = 0; bi < T; bi++)
        n += part[((size_t)linof(bi, T) << 9) + 256 + r];
    const float p = pospart[(T << 8) + r];

    float s = __logf(p + n + 1e-8f) - __logf(p);
    #pragma unroll
    for (int m = 1; m < 64; m <<= 1) s += __shfl_xor(s, m);
    __shared__ float red[2];
    if ((threadIdx.x & 63) == 0) red[threadIdx.x >> 6] = s;
    __syncthreads();
    if (threadIdx.x == 0)
        atomicAdd(out, (red[0] + red[1]) * (1.0f / (float)NROWS));
}

extern "C" void kernel_launch(void* const* d_in, const int* in_sizes, int n_in,
                              void* d_out, int out_size, void* d_ws, size_t ws_size,
                              hipStream_t stream) {
    (void)in_sizes; (void)n_in; (void)out_size; (void)ws_size;
    const float* emb = (const float*)d_in[0];
    unsigned short* En = (unsigned short*)d_ws;                          // 8 MB bf16
    float* pospart = (float*)((char*)d_ws + (size_t)NROWS * DIM * 2);    // 32 KB
    float* part    = pospart + 32 * 256;                                 // 1.05 MB

    knorm<<<NROWS / 4, 256, 0, stream>>>(emb, En, part, (float*)d_out);
    kgemm<<<768, 1024, 0, stream>>>(En, part, pospart);
    kred<<<64, 128, 0, stream>>>(part, pospart, (float*)d_out);
}